// Round 1
// baseline (119.340 us; speedup 1.0000x reference)
//
#include <hip/hip_runtime.h>

// Problem:
//   pos:    [1, 64, 1024]   float32
//   events: [2, 64, 131072] float32
//   out:    [2, 64, 131072] float32
// Semantics: out[b,e,t] = events[b,e,t-d_e] for t>=d_e else 0,
// where d_e = argmax(pos[0,e,:]) * (131072/1024).
//
// Single fused kernel: every block recomputes its event's argmax locally
// (pos row = 4 KB, L2/LLC-resident), then does its slice of the shifted copy.
// No d_ws, no cross-kernel dependency — deterministic given d_in only.
//
// R0 change vs previous best (118.7 us): STRIDE-INTERLEAVED work split.
// Previous version gave each block one contiguous 32 KB chunk; with
// round-robin block->CU dispatch, chunk index == CU mod 16, and copy
// probability grows linearly with chunk index -> ~2x per-CU traffic
// spread, wall time set by the copy-heavy CUs (~1.33x inflation).
// Now each block's 8 iterations are spread evenly across the whole row
// (stride 4096 float4), so every block carries the row-average zero/copy
// mix and per-CU traffic equalizes. Coalescing unchanged: 4 KB contiguous
// per block-iteration, reads stay 512 B aligned (d4 multiple of 32).
// Also: argmax is now wave-local (6-step shfl_xor butterfly over the full
// 1024-entry row per wave) -> no __syncthreads, no LDS in the prelude.

#define N_EVENTS 64
#define START_SIZE 1024
#define N_SAMPLES 131072
#define BATCH 2
#define FACTOR (N_SAMPLES / START_SIZE)      // 128 samples per pos slot
#define ROW_LEN4 (N_SAMPLES / 4)             // 32768 float4 per row
#define BLOCKS_PER_ROW 16
#define THREADS 256
#define SWEEP (BLOCKS_PER_ROW * THREADS)     // 4096 float4 per full-grid sweep
#define ITERS (ROW_LEN4 / SWEEP)             // 8 float4 per thread

__global__ __launch_bounds__(256) void dirac_fused_kernel(
        const float4* __restrict__ pos4,     // [64, 256] float4
        const float4* __restrict__ ev,       // [128, 32768] float4
        float4* __restrict__ out) {
    const int row   = blockIdx.x >> 4;       // 0..127  (b*64+e)
    const int chunk = blockIdx.x & (BLOCKS_PER_ROW - 1);
    const int e     = row & (N_EVENTS - 1);
    const int lane  = threadIdx.x & 63;

    // ---- wave-local argmax over pos[e][0..1023] (first-occurrence ties) ----
    // Each wave reads the whole 1024-float row (4 float4 per lane) and
    // reduces with a 64-lane butterfly. No barriers, no LDS.
    float v = -3.402823466e+38f;
    int   bi = 0x7fffffff;
    #pragma unroll
    for (int k = 0; k < 4; ++k) {
        const int f4 = k * 64 + lane;        // float4 index 0..255
        float4 p = pos4[e * 256 + f4];
        const int base = 4 * f4;
        if (p.x > v || (p.x == v && base     < bi)) { v = p.x; bi = base;     }
        if (p.y > v || (p.y == v && base + 1 < bi)) { v = p.y; bi = base + 1; }
        if (p.z > v || (p.z == v && base + 2 < bi)) { v = p.z; bi = base + 2; }
        if (p.w > v || (p.w == v && base + 3 < bi)) { v = p.w; bi = base + 3; }
    }
    #pragma unroll
    for (int off = 32; off >= 1; off >>= 1) {
        float ov = __shfl_xor(v, off, 64);
        int   oi = __shfl_xor(bi, off, 64);
        if (ov > v || (ov == v && oi < bi)) { v = ov; bi = oi; }
    }
    const int d4 = bi * (FACTOR / 4);        // float4-granular shift (mult of 32)

    // ---- stride-interleaved shifted copy: 8 x 4 KB segments spread
    //      evenly across the row, so zero/copy work is balanced per block ----
    const int rowbase = row * ROW_LEN4;
    const int colbase = chunk * THREADS + threadIdx.x;   // 0..4095
    #pragma unroll
    for (int it = 0; it < ITERS; ++it) {
        const int t4 = it * SWEEP + colbase;
        float4 val = make_float4(0.f, 0.f, 0.f, 0.f);
        if (t4 >= d4) {
            val = ev[rowbase + (t4 - d4)];
        }
        out[rowbase + t4] = val;
    }
}

extern "C" void kernel_launch(void* const* d_in, const int* in_sizes, int n_in,
                              void* d_out, int out_size, void* d_ws, size_t ws_size,
                              hipStream_t stream) {
    const float4* pos4 = (const float4*)d_in[0];
    const float4* ev   = (const float4*)d_in[1];
    float4* out = (float4*)d_out;

    const int nblocks = BATCH * N_EVENTS * BLOCKS_PER_ROW;   // 2048
    dirac_fused_kernel<<<nblocks, 256, 0, stream>>>(pos4, ev, out);
}